// Round 1
// baseline (2989.815 us; speedup 1.0000x reference)
//
#include <hip/hip_runtime.h>
#include <hip/hip_bf16.h>

// Sizes (fixed by the problem)
#define N_NODES  50000
#define N_HEDGES 25000
#define E_NN     800000
#define E_HH     400000
#define E_INC    200000
#define D        128

// ---------------------------------------------------------------------------
// Weight pre-swizzle: W[c][k] (128x128 row-major) -> grouped layout
//   out[cgrp*516 + k4*16 + ci*4 + kk],  c = cgrp*4+ci, k = k4*4+kk
// Per-cgrp pitch 516 floats (512 data + 4 pad) => LDS reads are 2-way (free).
// ---------------------------------------------------------------------------
__global__ __launch_bounds__(256) void swizzleW(
    const float* __restrict__ w0, const float* __restrict__ w1,
    const float* __restrict__ w2, const float* __restrict__ w3,
    float* __restrict__ out) {
  int id = blockIdx.x * 256 + threadIdx.x;      // 0 .. 65535
  int m = id >> 14, r = id & 16383;
  const float* w = (m == 0) ? w0 : (m == 1) ? w1 : (m == 2) ? w2 : w3;
  int c = r >> 7, k = r & 127;
  out[m * 16512 + (c >> 2) * 516 + (k >> 2) * 16 + (c & 3) * 4 + (k & 3)] = w[r];
}

// ---------------------------------------------------------------------------
// Zero fill (float4 granularity)
// ---------------------------------------------------------------------------
__global__ __launch_bounds__(256) void zero_f4(float4* __restrict__ p, int n4) {
  int i = blockIdx.x * 256 + threadIdx.x;
  if (i < n4) p[i] = make_float4(0.f, 0.f, 0.f, 0.f);
}

// ---------------------------------------------------------------------------
// Y[n,128] = X[n,128] @ W^T + b, W pre-swizzled (Wz).
// Tile: 64 rows x 64 cols per block (blockIdx.y selects col half).
// 256 threads, each computes a 4x4 register tile. VALU-bound.
// ---------------------------------------------------------------------------
__global__ __launch_bounds__(256) void linear64(
    const float* __restrict__ X, const float* __restrict__ Wz,
    const float* __restrict__ bias, float* __restrict__ Y, int n) {
  __shared__ float Ws[16 * 516];   // 16 col-groups of this half
  __shared__ float Xs[64 * 132];   // pitch 132 -> 2-way-free LDS reads
  int t = threadIdx.x;
  int r0 = blockIdx.x * 64;
  int cb = blockIdx.y * 64;

  // stage swizzled W half (8256 floats, contiguous, conflict-free)
  const float* wsrc = Wz + blockIdx.y * (16 * 516);
  for (int i = t * 4; i < 16 * 516; i += 1024)
    *(float4*)(Ws + i) = *(const float4*)(wsrc + i);

  // stage X rows r0..r0+63 (guarded, zero-filled past n)
  for (int q = t; q < 2048; q += 256) {
    int r = q >> 5, k4 = q & 31;
    float4 v = (r0 + r < n) ? *(const float4*)(X + (size_t)(r0 + r) * D + k4 * 4)
                            : make_float4(0.f, 0.f, 0.f, 0.f);
    *(float4*)(&Xs[r * 132 + k4 * 4]) = v;
  }
  __syncthreads();

  int tr = t >> 4, tc = t & 15;
  float acc[4][4] = {};
  const float* xbase = &Xs[tr * 4 * 132];
  const float* wbase = &Ws[tc * 516];

#pragma unroll 8
  for (int k4 = 0; k4 < 32; ++k4) {
    float4 xv[4], wv[4];
#pragma unroll
    for (int i = 0; i < 4; ++i) xv[i] = *(const float4*)(xbase + i * 132 + k4 * 4);
#pragma unroll
    for (int j = 0; j < 4; ++j) wv[j] = *(const float4*)(wbase + k4 * 16 + j * 4);
#pragma unroll
    for (int i = 0; i < 4; ++i)
#pragma unroll
      for (int j = 0; j < 4; ++j)
        acc[i][j] += xv[i].x * wv[j].x + xv[i].y * wv[j].y +
                     xv[i].z * wv[j].z + xv[i].w * wv[j].w;
  }

  int c0 = cb + tc * 4;
  float4 bv = *(const float4*)(bias + c0);
#pragma unroll
  for (int i = 0; i < 4; ++i) {
    int r = r0 + tr * 4 + i;
    if (r < n) {
      float4 o;
      o.x = acc[i][0] + bv.x; o.y = acc[i][1] + bv.y;
      o.z = acc[i][2] + bv.z; o.w = acc[i][3] + bv.w;
      *(float4*)(Y + (size_t)r * D + c0) = o;
    }
  }
}

// ---------------------------------------------------------------------------
// Edge scatter: out[recv] += conv[e] * P[send], 32 lanes per edge, float4.
// ---------------------------------------------------------------------------
__global__ __launch_bounds__(256) void scatter_add(
    const float* __restrict__ P, const float* __restrict__ conv,
    const int* __restrict__ snd, const int* __restrict__ rcv,
    float* __restrict__ out, int E) {
  int e = blockIdx.x * 8 + (threadIdx.x >> 5);
  if (e >= E) return;
  int lane = threadIdx.x & 31;
  float c = conv[e];
  int s = snd[e], r = rcv[e];
  float4 v = *(const float4*)(P + (size_t)s * D + lane * 4);
  float* o = out + (size_t)r * D + lane * 4;
  atomicAdd(o + 0, c * v.x);
  atomicAdd(o + 1, c * v.y);
  atomicAdd(o + 2, c * v.z);
  atomicAdd(o + 3, c * v.w);
}

// ---------------------------------------------------------------------------
// out = tanh(a * b), elementwise
// ---------------------------------------------------------------------------
__global__ __launch_bounds__(256) void combine_tanh(
    const float* __restrict__ a, const float* __restrict__ b,
    float* __restrict__ out, int n) {
  int i = (blockIdx.x * 256 + threadIdx.x) * 4;
  if (i < n) {
    float4 va = *(const float4*)(a + i);
    float4 vb = *(const float4*)(b + i);
    float4 o;
    o.x = tanhf(va.x * vb.x); o.y = tanhf(va.y * vb.y);
    o.z = tanhf(va.z * vb.z); o.w = tanhf(va.w * vb.w);
    *(float4*)(out + i) = o;
  }
}

extern "C" void kernel_launch(void* const* d_in, const int* in_sizes, int n_in,
                              void* d_out, int out_size, void* d_ws, size_t ws_size,
                              hipStream_t stream) {
  const float* node_features  = (const float*)d_in[0];
  const float* hedge_features = (const float*)d_in[1];
  const float* W_node_msg     = (const float*)d_in[2];
  const float* b_node_msg     = (const float*)d_in[3];
  const float* W_hedge_scale  = (const float*)d_in[4];
  const float* b_hedge_scale  = (const float*)d_in[5];
  const float* W_hedge_msg    = (const float*)d_in[6];
  const float* b_hedge_msg    = (const float*)d_in[7];
  const float* W_node_scale   = (const float*)d_in[8];
  const float* b_node_scale   = (const float*)d_in[9];
  const float* node_conv      = (const float*)d_in[10];
  const float* h2n_conv       = (const float*)d_in[11];
  const float* hedge_conv     = (const float*)d_in[12];
  const float* n2h_conv       = (const float*)d_in[13];
  const int*   node_snd       = (const int*)d_in[14];
  const int*   node_rcv       = (const int*)d_in[15];
  const int*   h2n_snd        = (const int*)d_in[16];
  const int*   h2n_rcv        = (const int*)d_in[17];
  const int*   hedge_snd      = (const int*)d_in[18];
  const int*   hedge_rcv      = (const int*)d_in[19];
  const int*   n2h_snd        = (const int*)d_in[20];
  const int*   n2h_rcv        = (const int*)d_in[21];

  float* out_node  = (float*)d_out;                       // 50000*128
  float* out_hedge = (float*)d_out + (size_t)N_NODES * D; // 25000*128

  // workspace layout (floats)
  float* ws = (float*)d_ws;
  float* Wz = ws;                         // 4 * 16512 = 66048
  float* P1 = ws + 66048;                 // 50000*128 = 6.4M
  float* P2 = P1 + (size_t)N_NODES * D;   // 25000*128 = 3.2M
  float* Sa = P2 + (size_t)N_HEDGES * D;  // 6.4M
  float* Sb = Sa + (size_t)N_NODES * D;   // 6.4M

  // 0. swizzle all four weight matrices
  swizzleW<<<256, 256, 0, stream>>>(W_node_msg, W_hedge_scale, W_hedge_msg,
                                    W_node_scale, Wz);

  // ---- Stage 1: NodeConvolution ----
  // zero Sa+Sb (contiguous 12.8M floats)
  zero_f4<<<12500, 256, 0, stream>>>((float4*)Sa, 3200000);
  // P1 = lin(node_features, W_node_msg); P2 = lin(hedge_features, W_hedge_scale)
  linear64<<<dim3(782, 2), 256, 0, stream>>>(node_features, Wz + 0 * 16512,
                                             b_node_msg, P1, N_NODES);
  linear64<<<dim3(391, 2), 256, 0, stream>>>(hedge_features, Wz + 1 * 16512,
                                             b_hedge_scale, P2, N_HEDGES);
  // Sa = segsum(node_conv * P1[snd] -> rcv); Sb = segsum(h2n_conv * P2[snd] -> rcv)
  scatter_add<<<E_NN / 8, 256, 0, stream>>>(P1, node_conv, node_snd, node_rcv, Sa, E_NN);
  scatter_add<<<E_INC / 8, 256, 0, stream>>>(P2, h2n_conv, h2n_snd, h2n_rcv, Sb, E_INC);
  // new_node = tanh(Sb * Sa)
  combine_tanh<<<6250, 256, 0, stream>>>(Sa, Sb, out_node, N_NODES * D);

  // ---- Stage 2: HedgeConvolution ----
  zero_f4<<<3125, 256, 0, stream>>>((float4*)Sa, 800000);
  zero_f4<<<3125, 256, 0, stream>>>((float4*)Sb, 800000);
  // P2 = lin(hedge_features, W_hedge_msg); P1 = lin(new_node, W_node_scale)
  linear64<<<dim3(391, 2), 256, 0, stream>>>(hedge_features, Wz + 2 * 16512,
                                             b_hedge_msg, P2, N_HEDGES);
  linear64<<<dim3(782, 2), 256, 0, stream>>>(out_node, Wz + 3 * 16512,
                                             b_node_scale, P1, N_NODES);
  scatter_add<<<E_HH / 8, 256, 0, stream>>>(P2, hedge_conv, hedge_snd, hedge_rcv, Sa, E_HH);
  scatter_add<<<E_INC / 8, 256, 0, stream>>>(P1, n2h_conv, n2h_snd, n2h_rcv, Sb, E_INC);
  // new_hedge = tanh(Sb * Sa)
  combine_tanh<<<3125, 256, 0, stream>>>(Sa, Sb, out_hedge, N_HEDGES * D);
}

// Round 2
// 843.467 us; speedup vs baseline: 3.5447x; 3.5447x over previous
//
#include <hip/hip_runtime.h>
#include <hip/hip_bf16.h>

#define N_NODES  50000
#define N_HEDGES 25000
#define E_NN     800000
#define E_HH     400000
#define E_INC    200000
#define D        128

// ---------------------------------------------------------------------------
// Weight pre-swizzle: W[c][k] (128x128 row-major) -> grouped layout
//   out[cgrp*516 + k4*16 + ci*4 + kk],  c = cgrp*4+ci, k = k4*4+kk
// ---------------------------------------------------------------------------
__global__ __launch_bounds__(256) void swizzleW(
    const float* __restrict__ w0, const float* __restrict__ w1,
    const float* __restrict__ w2, const float* __restrict__ w3,
    float* __restrict__ out) {
  int id = blockIdx.x * 256 + threadIdx.x;      // 0 .. 65535
  int m = id >> 14, r = id & 16383;
  const float* w = (m == 0) ? w0 : (m == 1) ? w1 : (m == 2) ? w2 : w3;
  int c = r >> 7, k = r & 127;
  out[m * 16512 + (c >> 2) * 516 + (k >> 2) * 16 + (c & 3) * 4 + (k & 3)] = w[r];
}

// ---------------------------------------------------------------------------
// Y[n,128] = X[n,128] @ W^T + b, W pre-swizzled (Wz). 64x64 tile, 4x4/thread.
// ---------------------------------------------------------------------------
__global__ __launch_bounds__(256) void linear64(
    const float* __restrict__ X, const float* __restrict__ Wz,
    const float* __restrict__ bias, float* __restrict__ Y, int n) {
  __shared__ float Ws[16 * 516];
  __shared__ float Xs[64 * 132];
  int t = threadIdx.x;
  int r0 = blockIdx.x * 64;
  int cb = blockIdx.y * 64;

  const float* wsrc = Wz + blockIdx.y * (16 * 516);
  for (int i = t * 4; i < 16 * 516; i += 1024)
    *(float4*)(Ws + i) = *(const float4*)(wsrc + i);

  for (int q = t; q < 2048; q += 256) {
    int r = q >> 5, k4 = q & 31;
    float4 v = (r0 + r < n) ? *(const float4*)(X + (size_t)(r0 + r) * D + k4 * 4)
                            : make_float4(0.f, 0.f, 0.f, 0.f);
    *(float4*)(&Xs[r * 132 + k4 * 4]) = v;
  }
  __syncthreads();

  int tr = t >> 4, tc = t & 15;
  float acc[4][4] = {};
  const float* xbase = &Xs[tr * 4 * 132];
  const float* wbase = &Ws[tc * 516];

#pragma unroll 8
  for (int k4 = 0; k4 < 32; ++k4) {
    float4 xv[4], wv[4];
#pragma unroll
    for (int i = 0; i < 4; ++i) xv[i] = *(const float4*)(xbase + i * 132 + k4 * 4);
#pragma unroll
    for (int j = 0; j < 4; ++j) wv[j] = *(const float4*)(wbase + k4 * 16 + j * 4);
#pragma unroll
    for (int i = 0; i < 4; ++i)
#pragma unroll
      for (int j = 0; j < 4; ++j)
        acc[i][j] += xv[i].x * wv[j].x + xv[i].y * wv[j].y +
                     xv[i].z * wv[j].z + xv[i].w * wv[j].w;
  }

  int c0 = cb + tc * 4;
  float4 bv = *(const float4*)(bias + c0);
#pragma unroll
  for (int i = 0; i < 4; ++i) {
    int r = r0 + tr * 4 + i;
    if (r < n) {
      float4 o;
      o.x = acc[i][0] + bv.x; o.y = acc[i][1] + bv.y;
      o.z = acc[i][2] + bv.z; o.w = acc[i][3] + bv.w;
      *(float4*)(Y + (size_t)r * D + c0) = o;
    }
  }
}

// ---------------------------------------------------------------------------
// CSR build: histogram -> exclusive scan (single block) -> atomic fill.
// ---------------------------------------------------------------------------
__global__ __launch_bounds__(256) void hist_k(const int* __restrict__ rcv,
                                              int* __restrict__ cnt, int E) {
  int i = blockIdx.x * 256 + threadIdx.x;
  if (i < E) atomicAdd(&cnt[rcv[i]], 1);
}

__global__ __launch_bounds__(1024) void exscan_k(const int* __restrict__ c,
                                                 int* __restrict__ offs,
                                                 int* __restrict__ cur, int n) {
  __shared__ int wsum[16];
  __shared__ int carrySh;
  int lane = threadIdx.x & 63, wid = threadIdx.x >> 6;
  if (threadIdx.x == 0) carrySh = 0;
  __syncthreads();
  for (int base = 0; base < n; base += 4096) {
    int i0 = base + threadIdx.x * 4;
    int v[4];
#pragma unroll
    for (int j = 0; j < 4; ++j) { int i = i0 + j; v[j] = (i < n) ? c[i] : 0; }
    int s = v[0] + v[1] + v[2] + v[3];
    int inc = s;
#pragma unroll
    for (int off = 1; off < 64; off <<= 1) {
      int tv = __shfl_up(inc, off, 64);
      if (lane >= off) inc += tv;
    }
    if (lane == 63) wsum[wid] = inc;
    __syncthreads();
    if (threadIdx.x == 0) {
      int run = 0;
      for (int w = 0; w < 16; ++w) { int x = wsum[w]; wsum[w] = run; run += x; }
    }
    __syncthreads();
    int run = carrySh + wsum[wid] + (inc - s);
#pragma unroll
    for (int j = 0; j < 4; ++j) {
      int i = i0 + j;
      if (i < n) { offs[i] = run; cur[i] = run; }
      run += v[j];
    }
    __syncthreads();
    if (threadIdx.x == 1023) carrySh = run;   // run = carry + chunk total
    __syncthreads();
  }
  if (threadIdx.x == 0) offs[n] = carrySh;
}

__global__ __launch_bounds__(256) void fill_k(const int* __restrict__ rcv,
                                              int* __restrict__ cur,
                                              int* __restrict__ eix, int E) {
  int i = blockIdx.x * 256 + threadIdx.x;
  if (i < E) {
    int p = atomicAdd(&cur[rcv[i]], 1);
    eix[p] = i;
  }
}

// ---------------------------------------------------------------------------
// Fused pull-mode double segment-sum + tanh combine.
// One 128-thread block per receiver row: out[r] = tanh(sumA * sumB)
//   sumA = sum_{e in CSRA(r)} convA[e] * Pa[sndA[e]]
//   sumB = sum_{e in CSRB(r)} convB[e] * Pb[sndB[e]]
// ---------------------------------------------------------------------------
__global__ __launch_bounds__(128) void gather_combine(
    const float* __restrict__ Pa, const float* __restrict__ convA,
    const int* __restrict__ sndA, const int* __restrict__ offsA,
    const int* __restrict__ eixA,
    const float* __restrict__ Pb, const float* __restrict__ convB,
    const int* __restrict__ sndB, const int* __restrict__ offsB,
    const int* __restrict__ eixB,
    float* __restrict__ out) {
  int r = blockIdx.x;
  int t = threadIdx.x;

  float sa = 0.f;
  int a0 = offsA[r], a1 = offsA[r + 1];
  int i = a0;
  for (; i + 1 < a1; i += 2) {
    int e0 = eixA[i], e1 = eixA[i + 1];
    int s0 = sndA[e0], s1 = sndA[e1];
    float c0 = convA[e0], c1 = convA[e1];
    sa += c0 * Pa[(size_t)s0 * D + t];
    sa += c1 * Pa[(size_t)s1 * D + t];
  }
  if (i < a1) {
    int e = eixA[i];
    sa += convA[e] * Pa[(size_t)sndA[e] * D + t];
  }

  float sb = 0.f;
  int b0 = offsB[r], b1 = offsB[r + 1];
  i = b0;
  for (; i + 1 < b1; i += 2) {
    int e0 = eixB[i], e1 = eixB[i + 1];
    int s0 = sndB[e0], s1 = sndB[e1];
    float c0 = convB[e0], c1 = convB[e1];
    sb += c0 * Pb[(size_t)s0 * D + t];
    sb += c1 * Pb[(size_t)s1 * D + t];
  }
  if (i < b1) {
    int e = eixB[i];
    sb += convB[e] * Pb[(size_t)sndB[e] * D + t];
  }

  out[(size_t)r * D + t] = tanhf(sa * sb);
}

extern "C" void kernel_launch(void* const* d_in, const int* in_sizes, int n_in,
                              void* d_out, int out_size, void* d_ws, size_t ws_size,
                              hipStream_t stream) {
  const float* node_features  = (const float*)d_in[0];
  const float* hedge_features = (const float*)d_in[1];
  const float* W_node_msg     = (const float*)d_in[2];
  const float* b_node_msg     = (const float*)d_in[3];
  const float* W_hedge_scale  = (const float*)d_in[4];
  const float* b_hedge_scale  = (const float*)d_in[5];
  const float* W_hedge_msg    = (const float*)d_in[6];
  const float* b_hedge_msg    = (const float*)d_in[7];
  const float* W_node_scale   = (const float*)d_in[8];
  const float* b_node_scale   = (const float*)d_in[9];
  const float* node_conv      = (const float*)d_in[10];
  const float* h2n_conv       = (const float*)d_in[11];
  const float* hedge_conv     = (const float*)d_in[12];
  const float* n2h_conv       = (const float*)d_in[13];
  const int*   node_snd       = (const int*)d_in[14];
  const int*   node_rcv       = (const int*)d_in[15];
  const int*   h2n_snd        = (const int*)d_in[16];
  const int*   h2n_rcv        = (const int*)d_in[17];
  const int*   hedge_snd      = (const int*)d_in[18];
  const int*   hedge_rcv      = (const int*)d_in[19];
  const int*   n2h_snd        = (const int*)d_in[20];
  const int*   n2h_rcv        = (const int*)d_in[21];

  float* out_node  = (float*)d_out;                       // 50000*128
  float* out_hedge = (float*)d_out + (size_t)N_NODES * D; // 25000*128

  // workspace layout
  float* ws = (float*)d_ws;
  float* Wz = ws;                                  // 66048 floats
  float* PA = ws + 66048;                          // 6.4M floats (P1 / P4)
  float* PB = PA + (size_t)N_NODES * D;            // 3.2M floats (P2 / P3)
  int* ibase   = (int*)(PB + (size_t)N_HEDGES * D);
  int* cnt     = ibase;                // 50001
  int* cur     = cnt + 50001;          // 50001
  int* offsNN  = cur + 50001;          // 50001
  int* offsH2N = offsNN + 50001;       // 50001
  int* offsHH  = offsH2N + 50001;      // 25001
  int* offsN2H = offsHH + 25001;       // 25001
  int* eixNN   = offsN2H + 25001;      // 800000
  int* eixH2N  = eixNN + E_NN;         // 200000
  int* eixHH   = eixH2N + E_INC;       // 400000
  int* eixN2H  = eixHH + E_HH;         // 200000

  // 0. weight swizzle
  swizzleW<<<256, 256, 0, stream>>>(W_node_msg, W_hedge_scale, W_hedge_msg,
                                    W_node_scale, Wz);

  // 1. CSR builds (receiver-indexed) for all four edge sets
  auto buildCSR = [&](const int* rcv, int E, int n, int* offs, int* eix) {
    hipMemsetAsync(cnt, 0, (size_t)n * sizeof(int), stream);
    hist_k<<<(E + 255) / 256, 256, 0, stream>>>(rcv, cnt, E);
    exscan_k<<<1, 1024, 0, stream>>>(cnt, offs, cur, n);
    fill_k<<<(E + 255) / 256, 256, 0, stream>>>(rcv, cur, eix, E);
  };
  buildCSR(node_rcv,  E_NN,  N_NODES,  offsNN,  eixNN);
  buildCSR(h2n_rcv,   E_INC, N_NODES,  offsH2N, eixH2N);
  buildCSR(hedge_rcv, E_HH,  N_HEDGES, offsHH,  eixHH);
  buildCSR(n2h_rcv,   E_INC, N_HEDGES, offsN2H, eixN2H);

  // ---- Stage 1: NodeConvolution ----
  linear64<<<dim3(782, 2), 256, 0, stream>>>(node_features, Wz + 0 * 16512,
                                             b_node_msg, PA, N_NODES);
  linear64<<<dim3(391, 2), 256, 0, stream>>>(hedge_features, Wz + 1 * 16512,
                                             b_hedge_scale, PB, N_HEDGES);
  gather_combine<<<N_NODES, 128, 0, stream>>>(
      PA, node_conv, node_snd, offsNN, eixNN,
      PB, h2n_conv, h2n_snd, offsH2N, eixH2N, out_node);

  // ---- Stage 2: HedgeConvolution ----
  linear64<<<dim3(391, 2), 256, 0, stream>>>(hedge_features, Wz + 2 * 16512,
                                             b_hedge_msg, PB, N_HEDGES);
  linear64<<<dim3(782, 2), 256, 0, stream>>>(out_node, Wz + 3 * 16512,
                                             b_node_scale, PA, N_NODES);
  gather_combine<<<N_HEDGES, 128, 0, stream>>>(
      PB, hedge_conv, hedge_snd, offsHH, eixHH,
      PA, n2h_conv, n2h_snd, offsN2H, eixN2H, out_hedge);
}

// Round 6
// 602.372 us; speedup vs baseline: 4.9634x; 1.4002x over previous
//
#include <hip/hip_runtime.h>
#include <hip/hip_bf16.h>

#define N_NODES  50000
#define N_HEDGES 25000
#define E_NN     800000
#define E_HH     400000
#define E_INC    200000
#define D        128

// ---------------------------------------------------------------------------
// Weight pre-swizzle: W[c][k] (128x128 row-major) -> grouped layout
//   out[cgrp*516 + k4*16 + ci*4 + kk],  c = cgrp*4+ci, k = k4*4+kk
// ---------------------------------------------------------------------------
__global__ __launch_bounds__(256) void swizzleW(
    const float* __restrict__ w0, const float* __restrict__ w1,
    const float* __restrict__ w2, const float* __restrict__ w3,
    float* __restrict__ out) {
  int id = blockIdx.x * 256 + threadIdx.x;      // 0 .. 65535
  int m = id >> 14, r = id & 16383;
  const float* w = (m == 0) ? w0 : (m == 1) ? w1 : (m == 2) ? w2 : w3;
  int c = r >> 7, k = r & 127;
  out[m * 16512 + (c >> 2) * 516 + (k >> 2) * 16 + (c & 3) * 4 + (k & 3)] = w[r];
}

// ---------------------------------------------------------------------------
// Y[n,128] = X[n,128] @ W^T + b, W pre-swizzled (Wz). 64x64 tile, 4x4/thread.
// ---------------------------------------------------------------------------
__global__ __launch_bounds__(256) void linear64(
    const float* __restrict__ X, const float* __restrict__ Wz,
    const float* __restrict__ bias, float* __restrict__ Y, int n) {
  __shared__ float Ws[16 * 516];
  __shared__ float Xs[64 * 132];
  int t = threadIdx.x;
  int r0 = blockIdx.x * 64;
  int cb = blockIdx.y * 64;

  const float* wsrc = Wz + blockIdx.y * (16 * 516);
  for (int i = t * 4; i < 16 * 516; i += 1024)
    *(float4*)(Ws + i) = *(const float4*)(wsrc + i);

  for (int q = t; q < 2048; q += 256) {
    int r = q >> 5, k4 = q & 31;
    float4 v = (r0 + r < n) ? *(const float4*)(X + (size_t)(r0 + r) * D + k4 * 4)
                            : make_float4(0.f, 0.f, 0.f, 0.f);
    *(float4*)(&Xs[r * 132 + k4 * 4]) = v;
  }
  __syncthreads();

  int tr = t >> 4, tc = t & 15;
  float acc[4][4] = {};
  const float* xbase = &Xs[tr * 4 * 132];
  const float* wbase = &Ws[tc * 516];

#pragma unroll 8
  for (int k4 = 0; k4 < 32; ++k4) {
    float4 xv[4], wv[4];
#pragma unroll
    for (int i = 0; i < 4; ++i) xv[i] = *(const float4*)(xbase + i * 132 + k4 * 4);
#pragma unroll
    for (int j = 0; j < 4; ++j) wv[j] = *(const float4*)(wbase + k4 * 16 + j * 4);
#pragma unroll
    for (int i = 0; i < 4; ++i)
#pragma unroll
      for (int j = 0; j < 4; ++j)
        acc[i][j] += xv[i].x * wv[j].x + xv[i].y * wv[j].y +
                     xv[i].z * wv[j].z + xv[i].w * wv[j].w;
  }

  int c0 = cb + tc * 4;
  float4 bv = *(const float4*)(bias + c0);
#pragma unroll
  for (int i = 0; i < 4; ++i) {
    int r = r0 + tr * 4 + i;
    if (r < n) {
      float4 o;
      o.x = acc[i][0] + bv.x; o.y = acc[i][1] + bv.y;
      o.z = acc[i][2] + bv.z; o.w = acc[i][3] + bv.w;
      *(float4*)(Y + (size_t)r * D + c0) = o;
    }
  }
}

// ---------------------------------------------------------------------------
// CSR build, consolidated. Block ranges over the 4 edge sets:
//   NN [0,3125)  H2N [3125,3907)  HH [3907,5470)  N2H [5470,6252)
// ---------------------------------------------------------------------------
#define B_NN   3125
#define B_H2N  782
#define B_HH   1563
#define B_N2H  782
#define B_TOT  (B_NN + B_H2N + B_HH + B_N2H)

__global__ __launch_bounds__(256) void hist4(
    const int* __restrict__ rNN, const int* __restrict__ rH2N,
    const int* __restrict__ rHH, const int* __restrict__ rN2H,
    int* __restrict__ cNN, int* __restrict__ cH2N,
    int* __restrict__ cHH, int* __restrict__ cN2H) {
  int b = blockIdx.x;
  const int* rcv; int* cnt; int E, base;
  if (b < B_NN)                { rcv = rNN;  cnt = cNN;  E = E_NN;  base = 0; }
  else if (b < B_NN + B_H2N)   { rcv = rH2N; cnt = cH2N; E = E_INC; base = B_NN; }
  else if (b < B_NN + B_H2N + B_HH) { rcv = rHH; cnt = cHH; E = E_HH; base = B_NN + B_H2N; }
  else                         { rcv = rN2H; cnt = cN2H; E = E_INC; base = B_NN + B_H2N + B_HH; }
  int i = (b - base) * 256 + threadIdx.x;
  if (i < E) atomicAdd(&cnt[rcv[i]], 1);
}

// 4 independent single-block exclusive scans (one per edge set)
__global__ __launch_bounds__(1024) void exscan4(
    const int* __restrict__ c0, int* __restrict__ o0, int* __restrict__ u0,
    const int* __restrict__ c1, int* __restrict__ o1, int* __restrict__ u1,
    const int* __restrict__ c2, int* __restrict__ o2, int* __restrict__ u2,
    const int* __restrict__ c3, int* __restrict__ o3, int* __restrict__ u3) {
  const int* c; int* offs; int* cur; int n;
  switch (blockIdx.x) {
    case 0:  c = c0; offs = o0; cur = u0; n = N_NODES;  break;
    case 1:  c = c1; offs = o1; cur = u1; n = N_NODES;  break;
    case 2:  c = c2; offs = o2; cur = u2; n = N_HEDGES; break;
    default: c = c3; offs = o3; cur = u3; n = N_HEDGES; break;
  }
  __shared__ int wsum[16];
  __shared__ int carrySh;
  int lane = threadIdx.x & 63, wid = threadIdx.x >> 6;
  if (threadIdx.x == 0) carrySh = 0;
  __syncthreads();
  for (int base = 0; base < n; base += 4096) {
    int i0 = base + threadIdx.x * 4;
    int v[4];
#pragma unroll
    for (int j = 0; j < 4; ++j) { int i = i0 + j; v[j] = (i < n) ? c[i] : 0; }
    int s = v[0] + v[1] + v[2] + v[3];
    int inc = s;
#pragma unroll
    for (int off = 1; off < 64; off <<= 1) {
      int tv = __shfl_up(inc, off, 64);
      if (lane >= off) inc += tv;
    }
    if (lane == 63) wsum[wid] = inc;
    __syncthreads();
    if (threadIdx.x == 0) {
      int run = 0;
      for (int w = 0; w < 16; ++w) { int x = wsum[w]; wsum[w] = run; run += x; }
    }
    __syncthreads();
    int run = carrySh + wsum[wid] + (inc - s);
#pragma unroll
    for (int j = 0; j < 4; ++j) {
      int i = i0 + j;
      if (i < n) { offs[i] = run; cur[i] = run; }
      run += v[j];
    }
    __syncthreads();
    if (threadIdx.x == 1023) carrySh = run;
    __syncthreads();
  }
  if (threadIdx.x == 0) offs[n] = carrySh;
}

// fill: write pre-permuted packed {snd, conv} pairs in CSR order
__global__ __launch_bounds__(256) void fill4(
    const int* __restrict__ rNN, const int* __restrict__ sNN,
    const float* __restrict__ vNN, int* __restrict__ uNN, int2* __restrict__ pNN,
    const int* __restrict__ rH2N, const int* __restrict__ sH2N,
    const float* __restrict__ vH2N, int* __restrict__ uH2N, int2* __restrict__ pH2N,
    const int* __restrict__ rHH, const int* __restrict__ sHH,
    const float* __restrict__ vHH, int* __restrict__ uHH, int2* __restrict__ pHH,
    const int* __restrict__ rN2H, const int* __restrict__ sN2H,
    const float* __restrict__ vN2H, int* __restrict__ uN2H, int2* __restrict__ pN2H) {
  int b = blockIdx.x;
  const int* rcv; const int* snd; const float* cv; int* cur; int2* pr; int E, base;
  if (b < B_NN)                { rcv = rNN;  snd = sNN;  cv = vNN;  cur = uNN;  pr = pNN;  E = E_NN;  base = 0; }
  else if (b < B_NN + B_H2N)   { rcv = rH2N; snd = sH2N; cv = vH2N; cur = uH2N; pr = pH2N; E = E_INC; base = B_NN; }
  else if (b < B_NN + B_H2N + B_HH) { rcv = rHH; snd = sHH; cv = vHH; cur = uHH; pr = pHH; E = E_HH; base = B_NN + B_H2N; }
  else                         { rcv = rN2H; snd = sN2H; cv = vN2H; cur = uN2H; pr = pN2H; E = E_INC; base = B_NN + B_H2N + B_HH; }
  int i = (b - base) * 256 + threadIdx.x;
  if (i < E) {
    int p = atomicAdd(&cur[rcv[i]], 1);
    pr[p] = make_int2(snd[i], __float_as_int(cv[i]));
  }
}

// ---------------------------------------------------------------------------
// Fused pull gather + tanh combine. ONE WAVE PER ROW, float2/lane.
// Deep unroll: batch 8 packed pairs, then 8 independent row loads in flight.
// ---------------------------------------------------------------------------
__global__ __launch_bounds__(256) void gather_combine2(
    const float* __restrict__ Pa, const int2* __restrict__ pairsA,
    const int* __restrict__ offsA,
    const float* __restrict__ Pb, const int2* __restrict__ pairsB,
    const int* __restrict__ offsB,
    float* __restrict__ out, int nrows) {
  int row = (blockIdx.x << 2) | (threadIdx.x >> 6);
  if (row >= nrows) return;
  int lane = threadIdx.x & 63;

  float sax = 0.f, say = 0.f;
  {
    int a0 = offsA[row], a1 = offsA[row + 1];
    int i = a0;
    for (; i + 8 <= a1; i += 8) {
      int2 p[8]; float2 v[8];
#pragma unroll
      for (int j = 0; j < 8; ++j) p[j] = pairsA[i + j];
#pragma unroll
      for (int j = 0; j < 8; ++j)
        v[j] = *(const float2*)(Pa + (size_t)p[j].x * D + lane * 2);
#pragma unroll
      for (int j = 0; j < 8; ++j) {
        float c = __int_as_float(p[j].y);
        sax += c * v[j].x; say += c * v[j].y;
      }
    }
    for (; i + 4 <= a1; i += 4) {
      int2 p[4]; float2 v[4];
#pragma unroll
      for (int j = 0; j < 4; ++j) p[j] = pairsA[i + j];
#pragma unroll
      for (int j = 0; j < 4; ++j)
        v[j] = *(const float2*)(Pa + (size_t)p[j].x * D + lane * 2);
#pragma unroll
      for (int j = 0; j < 4; ++j) {
        float c = __int_as_float(p[j].y);
        sax += c * v[j].x; say += c * v[j].y;
      }
    }
    for (; i < a1; ++i) {
      int2 p = pairsA[i];
      float c = __int_as_float(p.y);
      float2 v = *(const float2*)(Pa + (size_t)p.x * D + lane * 2);
      sax += c * v.x; say += c * v.y;
    }
  }

  float sbx = 0.f, sby = 0.f;
  {
    int b0 = offsB[row], b1 = offsB[row + 1];
    int i = b0;
    for (; i + 4 <= b1; i += 4) {
      int2 p[4]; float2 v[4];
#pragma unroll
      for (int j = 0; j < 4; ++j) p[j] = pairsB[i + j];
#pragma unroll
      for (int j = 0; j < 4; ++j)
        v[j] = *(const float2*)(Pb + (size_t)p[j].x * D + lane * 2);
#pragma unroll
      for (int j = 0; j < 4; ++j) {
        float c = __int_as_float(p[j].y);
        sbx += c * v[j].x; sby += c * v[j].y;
      }
    }
    for (; i < b1; ++i) {
      int2 p = pairsB[i];
      float c = __int_as_float(p.y);
      float2 v = *(const float2*)(Pb + (size_t)p.x * D + lane * 2);
      sbx += c * v.x; sby += c * v.y;
    }
  }

  float2 o;
  o.x = tanhf(sax * sbx);
  o.y = tanhf(say * sby);
  *(float2*)(out + (size_t)row * D + lane * 2) = o;
}

extern "C" void kernel_launch(void* const* d_in, const int* in_sizes, int n_in,
                              void* d_out, int out_size, void* d_ws, size_t ws_size,
                              hipStream_t stream) {
  const float* node_features  = (const float*)d_in[0];
  const float* hedge_features = (const float*)d_in[1];
  const float* W_node_msg     = (const float*)d_in[2];
  const float* b_node_msg     = (const float*)d_in[3];
  const float* W_hedge_scale  = (const float*)d_in[4];
  const float* b_hedge_scale  = (const float*)d_in[5];
  const float* W_hedge_msg    = (const float*)d_in[6];
  const float* b_hedge_msg    = (const float*)d_in[7];
  const float* W_node_scale   = (const float*)d_in[8];
  const float* b_node_scale   = (const float*)d_in[9];
  const float* node_conv      = (const float*)d_in[10];
  const float* h2n_conv       = (const float*)d_in[11];
  const float* hedge_conv     = (const float*)d_in[12];
  const float* n2h_conv       = (const float*)d_in[13];
  const int*   node_snd       = (const int*)d_in[14];
  const int*   node_rcv       = (const int*)d_in[15];
  const int*   h2n_snd        = (const int*)d_in[16];
  const int*   h2n_rcv        = (const int*)d_in[17];
  const int*   hedge_snd      = (const int*)d_in[18];
  const int*   hedge_rcv      = (const int*)d_in[19];
  const int*   n2h_snd        = (const int*)d_in[20];
  const int*   n2h_rcv        = (const int*)d_in[21];

  float* out_node  = (float*)d_out;
  float* out_hedge = (float*)d_out + (size_t)N_NODES * D;

  // workspace layout
  float* ws = (float*)d_ws;
  float* Wz = ws;                                   // 66048 floats
  float* PA = ws + 66048;                           // 6.4M floats
  float* PB = PA + (size_t)N_NODES * D;             // 3.2M floats
  int2* pairsNN  = (int2*)(PB + (size_t)N_HEDGES * D);  // 8-byte aligned
  int2* pairsH2N = pairsNN + E_NN;
  int2* pairsHH  = pairsH2N + E_INC;
  int2* pairsN2H = pairsHH + E_HH;
  int* cntNN  = (int*)(pairsN2H + E_INC);           // cnt block: 150000 ints
  int* cntH2N = cntNN + N_NODES;
  int* cntHH  = cntH2N + N_NODES;
  int* cntN2H = cntHH + N_HEDGES;
  int* curNN  = cntN2H + N_HEDGES;                  // cur block: 150000 ints
  int* curH2N = curNN + N_NODES;
  int* curHH  = curH2N + N_NODES;
  int* curN2H = curHH + N_HEDGES;
  int* offsNN  = curN2H + N_HEDGES;                 // offs: n+1 each
  int* offsH2N = offsNN + N_NODES + 1;
  int* offsHH  = offsH2N + N_NODES + 1;
  int* offsN2H = offsHH + N_HEDGES + 1;

  // 0. weight swizzle + zero counters
  swizzleW<<<256, 256, 0, stream>>>(W_node_msg, W_hedge_scale, W_hedge_msg,
                                    W_node_scale, Wz);
  hipMemsetAsync(cntNN, 0, (size_t)(2 * (N_NODES + N_HEDGES)) * sizeof(int), stream);

  // 1. CSR build (3 launches)
  hist4<<<B_TOT, 256, 0, stream>>>(node_rcv, h2n_rcv, hedge_rcv, n2h_rcv,
                                   cntNN, cntH2N, cntHH, cntN2H);
  exscan4<<<4, 1024, 0, stream>>>(cntNN, offsNN, curNN,
                                  cntH2N, offsH2N, curH2N,
                                  cntHH, offsHH, curHH,
                                  cntN2H, offsN2H, curN2H);
  fill4<<<B_TOT, 256, 0, stream>>>(
      node_rcv, node_snd, node_conv, curNN, pairsNN,
      h2n_rcv, h2n_snd, h2n_conv, curH2N, pairsH2N,
      hedge_rcv, hedge_snd, hedge_conv, curHH, pairsHH,
      n2h_rcv, n2h_snd, n2h_conv, curN2H, pairsN2H);

  // ---- Stage 1: NodeConvolution ----
  linear64<<<dim3(782, 2), 256, 0, stream>>>(node_features, Wz + 0 * 16512,
                                             b_node_msg, PA, N_NODES);
  linear64<<<dim3(391, 2), 256, 0, stream>>>(hedge_features, Wz + 1 * 16512,
                                             b_hedge_scale, PB, N_HEDGES);
  gather_combine2<<<N_NODES / 4, 256, 0, stream>>>(
      PA, pairsNN, offsNN, PB, pairsH2N, offsH2N, out_node, N_NODES);

  // ---- Stage 2: HedgeConvolution ----
  linear64<<<dim3(391, 2), 256, 0, stream>>>(hedge_features, Wz + 2 * 16512,
                                             b_hedge_msg, PB, N_HEDGES);
  linear64<<<dim3(782, 2), 256, 0, stream>>>(out_node, Wz + 3 * 16512,
                                             b_node_scale, PA, N_NODES);
  gather_combine2<<<N_HEDGES / 4, 256, 0, stream>>>(
      PB, pairsHH, offsHH, PA, pairsN2H, offsN2H, out_hedge, N_HEDGES);
}

// Round 10
// 547.953 us; speedup vs baseline: 5.4563x; 1.0993x over previous
//
#include <hip/hip_runtime.h>
#include <hip/hip_bf16.h>

#define N_NODES  50000
#define N_HEDGES 25000
#define E_NN     800000
#define E_HH     400000
#define E_INC    200000
#define D        128

// ---------------------------------------------------------------------------
// Weight pre-swizzle: W[c][k] (128x128 row-major) -> grouped layout
// ---------------------------------------------------------------------------
__global__ __launch_bounds__(256) void swizzleW(
    const float* __restrict__ w0, const float* __restrict__ w1,
    const float* __restrict__ w2, const float* __restrict__ w3,
    float* __restrict__ out) {
  int id = blockIdx.x * 256 + threadIdx.x;      // 0 .. 65535
  int m = id >> 14, r = id & 16383;
  const float* w = (m == 0) ? w0 : (m == 1) ? w1 : (m == 2) ? w2 : w3;
  int c = r >> 7, k = r & 127;
  out[m * 16512 + (c >> 2) * 516 + (k >> 2) * 16 + (c & 3) * 4 + (k & 3)] = w[r];
}

// ---------------------------------------------------------------------------
// Y[n,128] = X[n,128] @ W^T + b, W pre-swizzled (Wz). 64x64 tile, 4x4/thread.
// ---------------------------------------------------------------------------
__global__ __launch_bounds__(256) void linear64(
    const float* __restrict__ X, const float* __restrict__ Wz,
    const float* __restrict__ bias, float* __restrict__ Y, int n) {
  __shared__ float Ws[16 * 516];
  __shared__ float Xs[64 * 132];
  int t = threadIdx.x;
  int r0 = blockIdx.x * 64;
  int cb = blockIdx.y * 64;

  const float* wsrc = Wz + blockIdx.y * (16 * 516);
  for (int i = t * 4; i < 16 * 516; i += 1024)
    *(float4*)(Ws + i) = *(const float4*)(wsrc + i);

  for (int q = t; q < 2048; q += 256) {
    int r = q >> 5, k4 = q & 31;
    float4 v = (r0 + r < n) ? *(const float4*)(X + (size_t)(r0 + r) * D + k4 * 4)
                            : make_float4(0.f, 0.f, 0.f, 0.f);
    *(float4*)(&Xs[r * 132 + k4 * 4]) = v;
  }
  __syncthreads();

  int tr = t >> 4, tc = t & 15;
  float acc[4][4] = {};
  const float* xbase = &Xs[tr * 4 * 132];
  const float* wbase = &Ws[tc * 516];

#pragma unroll 8
  for (int k4 = 0; k4 < 32; ++k4) {
    float4 xv[4], wv[4];
#pragma unroll
    for (int i = 0; i < 4; ++i) xv[i] = *(const float4*)(xbase + i * 132 + k4 * 4);
#pragma unroll
    for (int j = 0; j < 4; ++j) wv[j] = *(const float4*)(wbase + k4 * 16 + j * 4);
#pragma unroll
    for (int i = 0; i < 4; ++i)
#pragma unroll
      for (int j = 0; j < 4; ++j)
        acc[i][j] += xv[i].x * wv[j].x + xv[i].y * wv[j].y +
                     xv[i].z * wv[j].z + xv[i].w * wv[j].w;
  }

  int c0 = cb + tc * 4;
  float4 bv = *(const float4*)(bias + c0);
#pragma unroll
  for (int i = 0; i < 4; ++i) {
    int r = r0 + tr * 4 + i;
    if (r < n) {
      float4 o;
      o.x = acc[i][0] + bv.x; o.y = acc[i][1] + bv.y;
      o.z = acc[i][2] + bv.z; o.w = acc[i][3] + bv.w;
      *(float4*)(Y + (size_t)r * D + c0) = o;
    }
  }
}

// ---------------------------------------------------------------------------
// hist4: per-receiver histogram (block ranges over the 4 edge sets)
// ---------------------------------------------------------------------------
#define B_NN   3125
#define B_H2N  782
#define B_HH   1563
#define B_N2H  782
#define B_TOT  (B_NN + B_H2N + B_HH + B_N2H)

__global__ __launch_bounds__(256) void hist4(
    const int* __restrict__ rNN, const int* __restrict__ rH2N,
    const int* __restrict__ rHH, const int* __restrict__ rN2H,
    int* __restrict__ cNN, int* __restrict__ cH2N,
    int* __restrict__ cHH, int* __restrict__ cN2H) {
  int b = blockIdx.x;
  const int* rcv; int* cnt; int E, base;
  if (b < B_NN)                { rcv = rNN;  cnt = cNN;  E = E_NN;  base = 0; }
  else if (b < B_NN + B_H2N)   { rcv = rH2N; cnt = cH2N; E = E_INC; base = B_NN; }
  else if (b < B_NN + B_H2N + B_HH) { rcv = rHH; cnt = cHH; E = E_HH; base = B_NN + B_H2N; }
  else                         { rcv = rN2H; cnt = cN2H; E = E_INC; base = B_NN + B_H2N + B_HH; }
  int i = (b - base) * 256 + threadIdx.x;
  if (i < E) atomicAdd(&cnt[rcv[i]], 1);
}

// ---------------------------------------------------------------------------
// Parallel 3-kernel exclusive scan over the 4 count arrays.
// ---------------------------------------------------------------------------
#define SB_NN0  0
#define SB_H2N0 25
#define SB_HH0  50
#define SB_N2H0 63
#define SB_TOT  76

__global__ __launch_bounds__(256) void scan_blk(
    const int* __restrict__ cNN, const int* __restrict__ cH2N,
    const int* __restrict__ cHH, const int* __restrict__ cN2H,
    int* __restrict__ oNN, int* __restrict__ oH2N,
    int* __restrict__ oHH, int* __restrict__ oN2H,
    int* __restrict__ bsum) {
  int b = blockIdx.x;
  const int* c; int* o; int n; int lb;
  if (b < SB_H2N0)       { c = cNN;  o = oNN;  n = N_NODES;  lb = b; }
  else if (b < SB_HH0)   { c = cH2N; o = oH2N; n = N_NODES;  lb = b - SB_H2N0; }
  else if (b < SB_N2H0)  { c = cHH;  o = oHH;  n = N_HEDGES; lb = b - SB_HH0; }
  else                   { c = cN2H; o = oN2H; n = N_HEDGES; lb = b - SB_N2H0; }
  int t = threadIdx.x, lane = t & 63, wid = t >> 6;
  int i0 = lb * 2048 + t * 8;
  int v[8]; int s = 0;
#pragma unroll
  for (int j = 0; j < 8; ++j) { int i = i0 + j; v[j] = (i < n) ? c[i] : 0; s += v[j]; }
  int inc = s;
#pragma unroll
  for (int off = 1; off < 64; off <<= 1) {
    int tv = __shfl_up(inc, off, 64);
    if (lane >= off) inc += tv;
  }
  __shared__ int wsum[4];
  if (lane == 63) wsum[wid] = inc;
  __syncthreads();
  if (t == 0) {
    int run = 0;
    for (int w = 0; w < 4; ++w) { int x = wsum[w]; wsum[w] = run; run += x; }
  }
  __syncthreads();
  int run = wsum[wid] + (inc - s);
#pragma unroll
  for (int j = 0; j < 8; ++j) { int i = i0 + j; if (i < n) o[i] = run; run += v[j]; }
  if (t == 255) bsum[b] = run;   // chunk total
}

__global__ void scan_bsum(int* __restrict__ bsum,
                          int* __restrict__ oNN, int* __restrict__ oH2N,
                          int* __restrict__ oHH, int* __restrict__ oN2H) {
  int a = threadIdx.x;
  if (a >= 4) return;
  int base = (a == 0) ? SB_NN0 : (a == 1) ? SB_H2N0 : (a == 2) ? SB_HH0 : SB_N2H0;
  int cnt  = (a < 2) ? 25 : 13;
  int run = 0;
  for (int i = 0; i < cnt; ++i) { int x = bsum[base + i]; bsum[base + i] = run; run += x; }
  int* o = (a == 0) ? oNN : (a == 1) ? oH2N : (a == 2) ? oHH : oN2H;
  int n = (a < 2) ? N_NODES : N_HEDGES;
  o[n] = run;
}

__global__ __launch_bounds__(256) void scan_add(
    int* __restrict__ oNN, int* __restrict__ oH2N,
    int* __restrict__ oHH, int* __restrict__ oN2H,
    int* __restrict__ uNN, int* __restrict__ uH2N,
    int* __restrict__ uHH, int* __restrict__ uN2H,
    const int* __restrict__ bsum) {
  int b = blockIdx.x;
  int* o; int* u; int n; int lb;
  if (b < SB_H2N0)       { o = oNN;  u = uNN;  n = N_NODES;  lb = b; }
  else if (b < SB_HH0)   { o = oH2N; u = uH2N; n = N_NODES;  lb = b - SB_H2N0; }
  else if (b < SB_N2H0)  { o = oHH;  u = uHH;  n = N_HEDGES; lb = b - SB_HH0; }
  else                   { o = oN2H; u = uN2H; n = N_HEDGES; lb = b - SB_N2H0; }
  int add = bsum[b];
  int i0 = lb * 2048 + threadIdx.x * 8;
#pragma unroll
  for (int j = 0; j < 8; ++j) {
    int i = i0 + j;
    if (i < n) { int x = o[i] + add; o[i] = x; u[i] = x; }
  }
}

// ---------------------------------------------------------------------------
// Bucketed CSR fill. Bucket = rcv >> 6 (64 receivers); base = offs[bk*64].
// ---------------------------------------------------------------------------
#define NB_NN   782
#define NB_H2N  782
#define NB_HH   391
#define NB_N2H  391
#define NB_TOT  (NB_NN + NB_H2N + NB_HH + NB_N2H)   // 2346
#define NB_MAX  782

#define REC_NN  0
#define REC_H2N 800000
#define REC_HH  1000000
#define REC_N2H 1400000

__global__ __launch_bounds__(256) void initb(
    const int* __restrict__ oNN, const int* __restrict__ oH2N,
    const int* __restrict__ oHH, const int* __restrict__ oN2H,
    int* __restrict__ bcur) {
  int i = blockIdx.x * 256 + threadIdx.x;
  if (i >= NB_TOT) return;
  int v;
  if (i < NB_NN)                        v = oNN[i << 6];
  else if (i < NB_NN + NB_H2N)          v = oH2N[(i - NB_NN) << 6];
  else if (i < NB_NN + NB_H2N + NB_HH)  v = oHH[(i - NB_NN - NB_H2N) << 6];
  else                                  v = oN2H[(i - NB_NN - NB_H2N - NB_HH) << 6];
  bcur[i] = v;
}

#define PA_NN0  0
#define PA_H2N0 391
#define PA_HH0  489
#define PA_N2H0 685
#define PA_TOT  783

__global__ __launch_bounds__(256) void passA(
    const int* __restrict__ sNN, const int* __restrict__ rNN, const float* __restrict__ vNN,
    const int* __restrict__ sH2N, const int* __restrict__ rH2N, const float* __restrict__ vH2N,
    const int* __restrict__ sHH, const int* __restrict__ rHH, const float* __restrict__ vHH,
    const int* __restrict__ sN2H, const int* __restrict__ rN2H, const float* __restrict__ vN2H,
    int* __restrict__ bcur, int2* __restrict__ rec_sc, int* __restrict__ rec_r) {
  __shared__ int hist[NB_MAX];
  __shared__ int gbase[NB_MAX];
  __shared__ int lcur[NB_MAX];
  int b = blockIdx.x;
  const int* snd; const int* rcv; const float* conv;
  int E, blkbase, bcoff, recoff, NB;
  if (b < PA_H2N0)      { snd=sNN;  rcv=rNN;  conv=vNN;  E=E_NN;  blkbase=PA_NN0;  bcoff=0;    recoff=REC_NN;  NB=NB_NN; }
  else if (b < PA_HH0)  { snd=sH2N; rcv=rH2N; conv=vH2N; E=E_INC; blkbase=PA_H2N0; bcoff=782;  recoff=REC_H2N; NB=NB_H2N; }
  else if (b < PA_N2H0) { snd=sHH;  rcv=rHH;  conv=vHH;  E=E_HH;  blkbase=PA_HH0;  bcoff=1564; recoff=REC_HH;  NB=NB_HH; }
  else                  { snd=sN2H; rcv=rN2H; conv=vN2H; E=E_INC; blkbase=PA_N2H0; bcoff=1955; recoff=REC_N2H; NB=NB_N2H; }
  int t = threadIdx.x;
  int estart = (b - blkbase) * 2048;

  int rv[8]; int sd[8]; float cv[8]; int bk[8]; bool ok[8];
#pragma unroll
  for (int j = 0; j < 8; ++j) {
    int e = estart + t + j * 256;
    ok[j] = e < E;
    int r = ok[j] ? rcv[e] : 0;
    rv[j] = r;
    bk[j] = r >> 6;
    sd[j] = ok[j] ? snd[e] : 0;
    cv[j] = ok[j] ? conv[e] : 0.f;
  }
  for (int i = t; i < NB; i += 256) hist[i] = 0;
  __syncthreads();
#pragma unroll
  for (int j = 0; j < 8; ++j) if (ok[j]) atomicAdd(&hist[bk[j]], 1);
  __syncthreads();
  for (int i = t; i < NB; i += 256) {
    int h = hist[i];
    gbase[i] = h ? atomicAdd(&bcur[bcoff + i], h) : 0;
    lcur[i] = 0;
  }
  __syncthreads();
#pragma unroll
  for (int j = 0; j < 8; ++j) if (ok[j]) {
    int rk = atomicAdd(&lcur[bk[j]], 1);
    int g = recoff + gbase[bk[j]] + rk;
    rec_sc[g] = make_int2(sd[j], __float_as_int(cv[j]));
    rec_r[g] = rv[j];
  }
}

__global__ __launch_bounds__(256) void passB(
    const int2* __restrict__ rec_sc, const int* __restrict__ rec_r,
    const int* __restrict__ oNN, const int* __restrict__ oH2N,
    const int* __restrict__ oHH, const int* __restrict__ oN2H,
    int* __restrict__ uNN, int* __restrict__ uH2N,
    int* __restrict__ uHH, int* __restrict__ uN2H,
    int2* __restrict__ pairs) {
  int b = blockIdx.x;
  const int* offs; int* cur; int n, lb, recoff;
  if (b < NB_NN)                        { offs = oNN;  cur = uNN;  n = N_NODES;  lb = b;                          recoff = REC_NN; }
  else if (b < NB_NN + NB_H2N)          { offs = oH2N; cur = uH2N; n = N_NODES;  lb = b - NB_NN;                  recoff = REC_H2N; }
  else if (b < NB_NN + NB_H2N + NB_HH)  { offs = oHH;  cur = uHH;  n = N_HEDGES; lb = b - NB_NN - NB_H2N;         recoff = REC_HH; }
  else                                  { offs = oN2H; cur = uN2H; n = N_HEDGES; lb = b - NB_NN - NB_H2N - NB_HH; recoff = REC_N2H; }
  int r0 = lb << 6;
  int r1 = min(r0 + 64, n);
  int base = offs[r0], end = offs[r1];
  for (int i = base + (int)threadIdx.x; i < end; i += 256) {
    int2 sc = rec_sc[recoff + i];
    int rvv = rec_r[recoff + i];
    int p = atomicAdd(&cur[rvv], 1);
    pairs[recoff + p] = sc;
  }
}

// ---------------------------------------------------------------------------
// Fused pull gather + tanh combine. ONE WAVE PER ROW, float2/lane, unroll 8.
// ---------------------------------------------------------------------------
__global__ __launch_bounds__(256) void gather_combine2(
    const float* __restrict__ Pa, const int2* __restrict__ pairsA,
    const int* __restrict__ offsA,
    const float* __restrict__ Pb, const int2* __restrict__ pairsB,
    const int* __restrict__ offsB,
    float* __restrict__ out, int nrows) {
  int row = (blockIdx.x << 2) | (threadIdx.x >> 6);
  if (row >= nrows) return;
  int lane = threadIdx.x & 63;

  float sax = 0.f, say = 0.f;
  {
    int a0 = offsA[row], a1 = offsA[row + 1];
    int i = a0;
    for (; i + 8 <= a1; i += 8) {
      int2 p[8]; float2 v[8];
#pragma unroll
      for (int j = 0; j < 8; ++j) p[j] = pairsA[i + j];
#pragma unroll
      for (int j = 0; j < 8; ++j)
        v[j] = *(const float2*)(Pa + (size_t)p[j].x * D + lane * 2);
#pragma unroll
      for (int j = 0; j < 8; ++j) {
        float c = __int_as_float(p[j].y);
        sax += c * v[j].x; say += c * v[j].y;
      }
    }
    for (; i + 4 <= a1; i += 4) {
      int2 p[4]; float2 v[4];
#pragma unroll
      for (int j = 0; j < 4; ++j) p[j] = pairsA[i + j];
#pragma unroll
      for (int j = 0; j < 4; ++j)
        v[j] = *(const float2*)(Pa + (size_t)p[j].x * D + lane * 2);
#pragma unroll
      for (int j = 0; j < 4; ++j) {
        float c = __int_as_float(p[j].y);
        sax += c * v[j].x; say += c * v[j].y;
      }
    }
    for (; i < a1; ++i) {
      int2 p = pairsA[i];
      float c = __int_as_float(p.y);
      float2 v = *(const float2*)(Pa + (size_t)p.x * D + lane * 2);
      sax += c * v.x; say += c * v.y;
    }
  }

  float sbx = 0.f, sby = 0.f;
  {
    int b0 = offsB[row], b1 = offsB[row + 1];
    int i = b0;
    for (; i + 4 <= b1; i += 4) {
      int2 p[4]; float2 v[4];
#pragma unroll
      for (int j = 0; j < 4; ++j) p[j] = pairsB[i + j];
#pragma unroll
      for (int j = 0; j < 4; ++j)
        v[j] = *(const float2*)(Pb + (size_t)p[j].x * D + lane * 2);
#pragma unroll
      for (int j = 0; j < 4; ++j) {
        float c = __int_as_float(p[j].y);
        sbx += c * v[j].x; sby += c * v[j].y;
      }
    }
    for (; i < b1; ++i) {
      int2 p = pairsB[i];
      float c = __int_as_float(p.y);
      float2 v = *(const float2*)(Pb + (size_t)p.x * D + lane * 2);
      sbx += c * v.x; sby += c * v.y;
    }
  }

  float2 o;
  o.x = tanhf(sax * sbx);
  o.y = tanhf(say * sby);
  *(float2*)(out + (size_t)row * D + lane * 2) = o;
}

extern "C" void kernel_launch(void* const* d_in, const int* in_sizes, int n_in,
                              void* d_out, int out_size, void* d_ws, size_t ws_size,
                              hipStream_t stream) {
  const float* node_features  = (const float*)d_in[0];
  const float* hedge_features = (const float*)d_in[1];
  const float* W_node_msg     = (const float*)d_in[2];
  const float* b_node_msg     = (const float*)d_in[3];
  const float* W_hedge_scale  = (const float*)d_in[4];
  const float* b_hedge_scale  = (const float*)d_in[5];
  const float* W_hedge_msg    = (const float*)d_in[6];
  const float* b_hedge_msg    = (const float*)d_in[7];
  const float* W_node_scale   = (const float*)d_in[8];
  const float* b_node_scale   = (const float*)d_in[9];
  const float* node_conv      = (const float*)d_in[10];
  const float* h2n_conv       = (const float*)d_in[11];
  const float* hedge_conv     = (const float*)d_in[12];
  const float* n2h_conv       = (const float*)d_in[13];
  const int*   node_snd       = (const int*)d_in[14];
  const int*   node_rcv       = (const int*)d_in[15];
  const int*   h2n_snd        = (const int*)d_in[16];
  const int*   h2n_rcv        = (const int*)d_in[17];
  const int*   hedge_snd      = (const int*)d_in[18];
  const int*   hedge_rcv      = (const int*)d_in[19];
  const int*   n2h_snd        = (const int*)d_in[20];
  const int*   n2h_rcv        = (const int*)d_in[21];

  float* out_node  = (float*)d_out;
  float* out_hedge = (float*)d_out + (size_t)N_NODES * D;

  // workspace layout
  float* ws = (float*)d_ws;
  float* Wz = ws;                                   // 66048 floats
  float* PA = ws + 66048;                           // 6.4M floats
  float* PB = PA + (size_t)N_NODES * D;             // 3.2M floats
  int2* pairs   = (int2*)(PB + (size_t)N_HEDGES * D);   // 1.6M int2 (NN|H2N|HH|N2H)
  int2* rec_sc  = pairs + 1600000;                      // 1.6M int2
  int*  rec_r   = (int*)(rec_sc + 1600000);             // 1.6M int
  int* cntNN  = rec_r + 1600000;                    // cnt block: 150000 ints
  int* cntH2N = cntNN + N_NODES;
  int* cntHH  = cntH2N + N_NODES;
  int* cntN2H = cntHH + N_HEDGES;
  int* curNN  = cntN2H + N_HEDGES;                  // cur block: 150000 ints
  int* curH2N = curNN + N_NODES;
  int* curHH  = curH2N + N_NODES;
  int* curN2H = curHH + N_HEDGES;
  int* offsNN  = curN2H + N_HEDGES;                 // offs: n+1 each
  int* offsH2N = offsNN + N_NODES + 1;
  int* offsHH  = offsH2N + N_NODES + 1;
  int* offsN2H = offsHH + N_HEDGES + 1;
  int* bsum    = offsN2H + N_HEDGES + 1;            // 76 ints
  int* bcur    = bsum + SB_TOT;                     // 2346 ints

  int2* pairsNN  = pairs;
  int2* pairsH2N = pairs + REC_H2N;
  int2* pairsHH  = pairs + REC_HH;
  int2* pairsN2H = pairs + REC_N2H;

  // 0. weight swizzle + zero counters
  swizzleW<<<256, 256, 0, stream>>>(W_node_msg, W_hedge_scale, W_hedge_msg,
                                    W_node_scale, Wz);
  hipMemsetAsync(cntNN, 0, (size_t)(2 * (N_NODES + N_HEDGES)) * sizeof(int), stream);

  // 1. CSR build: hist -> parallel scan -> bucket init -> partition -> fine fill
  hist4<<<B_TOT, 256, 0, stream>>>(node_rcv, h2n_rcv, hedge_rcv, n2h_rcv,
                                   cntNN, cntH2N, cntHH, cntN2H);
  scan_blk<<<SB_TOT, 256, 0, stream>>>(cntNN, cntH2N, cntHH, cntN2H,
                                       offsNN, offsH2N, offsHH, offsN2H, bsum);
  scan_bsum<<<1, 64, 0, stream>>>(bsum, offsNN, offsH2N, offsHH, offsN2H);
  scan_add<<<SB_TOT, 256, 0, stream>>>(offsNN, offsH2N, offsHH, offsN2H,
                                       curNN, curH2N, curHH, curN2H, bsum);
  initb<<<(NB_TOT + 255) / 256, 256, 0, stream>>>(offsNN, offsH2N, offsHH, offsN2H, bcur);
  passA<<<PA_TOT, 256, 0, stream>>>(
      node_snd, node_rcv, node_conv,
      h2n_snd, h2n_rcv, h2n_conv,
      hedge_snd, hedge_rcv, hedge_conv,
      n2h_snd, n2h_rcv, n2h_conv,
      bcur, rec_sc, rec_r);
  passB<<<NB_TOT, 256, 0, stream>>>(
      rec_sc, rec_r,
      offsNN, offsH2N, offsHH, offsN2H,
      curNN, curH2N, curHH, curN2H, pairs);

  // ---- Stage 1: NodeConvolution ----
  linear64<<<dim3(782, 2), 256, 0, stream>>>(node_features, Wz + 0 * 16512,
                                             b_node_msg, PA, N_NODES);
  linear64<<<dim3(391, 2), 256, 0, stream>>>(hedge_features, Wz + 1 * 16512,
                                             b_hedge_scale, PB, N_HEDGES);
  gather_combine2<<<N_NODES / 4, 256, 0, stream>>>(
      PA, pairsNN, offsNN, PB, pairsH2N, offsH2N, out_node, N_NODES);

  // ---- Stage 2: HedgeConvolution ----
  linear64<<<dim3(391, 2), 256, 0, stream>>>(hedge_features, Wz + 2 * 16512,
                                             b_hedge_msg, PB, N_HEDGES);
  linear64<<<dim3(782, 2), 256, 0, stream>>>(out_node, Wz + 3 * 16512,
                                             b_node_scale, PA, N_NODES);
  gather_combine2<<<N_HEDGES / 4, 256, 0, stream>>>(
      PB, pairsHH, offsHH, PA, pairsN2H, offsN2H, out_hedge, N_HEDGES);
}